// Round 3
// baseline (293.470 us; speedup 1.0000x reference)
//
#include <hip/hip_runtime.h>
#include <hip/hip_bf16.h>

// Problem dims
#define B_  2
#define C_  256
#define N_  4096
#define R_  8
#define G_  4
#define CG_ 64

typedef __attribute__((ext_vector_type(8))) short short8;
typedef __attribute__((ext_vector_type(4))) float f32x4;

#define MFMA16(a, b, c) __builtin_amdgcn_mfma_f32_16x16x32_bf16((a), (b), (c), 0, 0, 0)
#define EXP2F(x) __builtin_amdgcn_exp2f(x)
#define LOG2E 1.44269504088896f

// -------- bf16 pack helpers (rne via HW cvt) --------
__device__ inline unsigned int pk2(float a, float b) {
    union { __hip_bfloat162 h; unsigned int u; } cv;
    cv.h = __float22bfloat162_rn(float2{a, b});
    return cv.u;
}
__device__ inline unsigned short f2bf(float f) {
    union { __hip_bfloat16 h; unsigned short u; } cv;
    cv.h = __float2bfloat16(f);
    return cv.u;
}

// Workspace layout:
//  qT  bf16 [d][b][n][8]  (log2e folded)  : ushort 0        (131072)
//  kT  bf16 [d][b][m][8]                  : ushort 131072   (131072)
//  v   bf16 [d][b][c][n]  (plain, no Z)   : ushort 262144   (4194304)
//  l2z f32  [d][b][n] = -log2(Z)          : float  2228224  (16384)
#define QT_OFF   0
#define KT_OFF   131072
#define VZ_OFF   262144
#define L2Z_OFFF 2228224
// total ~9.0 MB (< round-1's 17.9 MB known-safe footprint)

// ---------------------------------------------------------------------------
// Kernel 1: fused projections + grouped conv, MFMA-based. Reads f once.
// s = blockIdx.z>>1 (0: x=fL, 1: x=fU), b = blockIdx.z&1, n-tile 64.
// Outputs: qT[dq=s] (*log2e), kT[dk=1-s], v[dv=1-s].
// LDS: x staged bf16 [c 256][n 64 +pad]; 8 B-frags/wave shared by proj+conv.
// ---------------------------------------------------------------------------
#define XS_STRIDE 72

__global__ __launch_bounds__(256) void fused_pre(
    const float* __restrict__ fL, const float* __restrict__ fU,
    const float* __restrict__ qLw, const float* __restrict__ qLb,
    const float* __restrict__ kUw, const float* __restrict__ kUb,
    const float* __restrict__ vUw, const float* __restrict__ vUb,
    const float* __restrict__ qUw, const float* __restrict__ qUb,
    const float* __restrict__ kLw, const float* __restrict__ kLb,
    const float* __restrict__ vLw, const float* __restrict__ vLb,
    unsigned short* __restrict__ wsu)
{
    const int s  = blockIdx.z >> 1;
    const int b  = blockIdx.z & 1;
    const int n0 = blockIdx.x * 64;
    const int t  = threadIdx.x;

    const float* x  = (s ? fU : fL) + (size_t)b * C_ * N_;
    const float* wq = s ? qUw : qLw;
    const float* bq = s ? qUb : qLb;
    const float* wk = s ? kUw : kLw;
    const float* bk = s ? kUb : kLb;
    const float* wv = s ? vUw : vLw;
    const float* bv = s ? vUb : vLb;
    const int dq = s, dk = 1 - s, dv = 1 - s;

    __shared__ unsigned short xs[C_ * XS_STRIDE];

    // ---- stage x tile as bf16 [c][n] ----
#pragma unroll
    for (int j = 0; j < 16; j++) {
        const int i  = t + 256 * j;
        const int c  = i >> 4;
        const int nc = (i & 15) * 4;
        const float4 xv = *reinterpret_cast<const float4*>(x + (size_t)c * N_ + n0 + nc);
        uint2 p;
        p.x = pk2(xv.x, xv.y);
        p.y = pk2(xv.z, xv.w);
        *reinterpret_cast<uint2*>(xs + c * XS_STRIDE + nc) = p;
    }
    __syncthreads();

    const int w  = t >> 6;
    const int l  = t & 63;
    const int lm = l & 15;
    const int lg = l >> 4;
    const int nrow = w * 16 + lm;          // n-local handled by this lane
    const int n = n0 + nrow;

    // ---- build the 8 B-frags (x^T fragments), shared by proj and conv ----
    short8 bf[8];
#pragma unroll
    for (int kc = 0; kc < 8; kc++) {
        const int cbase = kc * 32 + lg * 8;
        union { unsigned short u[8]; short8 v; } bb;
#pragma unroll
        for (int cc = 0; cc < 8; cc++)
            bb.u[cc] = xs[(cbase + cc) * XS_STRIDE + nrow];
        bf[kc] = bb.v;
    }

    // ---- proj: 16 output rows (0-7 q, 8-15 k) over full C ----
    {
        const int o = lm;
        const float* wrow = (o < 8) ? (wq + o * C_) : (wk + (o - 8) * C_);
        f32x4 pa = {0.f, 0.f, 0.f, 0.f};
#pragma unroll
        for (int kc = 0; kc < 8; kc++) {
            const int cb = kc * 32 + lg * 8;
            const float4 w0 = *reinterpret_cast<const float4*>(wrow + cb);
            const float4 w1 = *reinterpret_cast<const float4*>(wrow + cb + 4);
            union { unsigned int u[4]; short8 v; } aw;
            aw.u[0] = pk2(w0.x, w0.y); aw.u[1] = pk2(w0.z, w0.w);
            aw.u[2] = pk2(w1.x, w1.y); aw.u[3] = pk2(w1.z, w1.w);
            pa = MFMA16(aw.v, bf[kc], pa);
        }
        // D rows o' = lg*4+r (lg<2 -> q, else k), col n
        float v0, v1, v2, v3;
        if (lg < 2) {
            v0 = (pa[0] + bq[lg * 4 + 0]) * LOG2E;
            v1 = (pa[1] + bq[lg * 4 + 1]) * LOG2E;
            v2 = (pa[2] + bq[lg * 4 + 2]) * LOG2E;
            v3 = (pa[3] + bq[lg * 4 + 3]) * LOG2E;
            uint2 p; p.x = pk2(v0, v1); p.y = pk2(v2, v3);
            *reinterpret_cast<uint2*>(wsu + QT_OFF +
                ((size_t)(dq * B_ + b) * N_ + n) * 8 + lg * 4) = p;
        } else {
            const int o2 = (lg - 2) * 4;
            v0 = pa[0] + bk[o2 + 0];
            v1 = pa[1] + bk[o2 + 1];
            v2 = pa[2] + bk[o2 + 2];
            v3 = pa[3] + bk[o2 + 3];
            uint2 p; p.x = pk2(v0, v1); p.y = pk2(v2, v3);
            *reinterpret_cast<uint2*>(wsu + KT_OFF +
                ((size_t)(dk * B_ + b) * N_ + n) * 8 + o2) = p;
        }
    }

    // ---- grouped conv: per group g, 64 out-channels from 64 in-channels ----
    unsigned short* vout = wsu + VZ_OFF + (size_t)(dv * B_ + b) * C_ * N_;
#pragma unroll
    for (int g4 = 0; g4 < 4; g4++) {
#pragma unroll
        for (int oc = 0; oc < 4; oc++) {
            f32x4 ca = {0.f, 0.f, 0.f, 0.f};
#pragma unroll
            for (int kc2 = 0; kc2 < 2; kc2++) {
                const float* wr = wv + g4 * (CG_ * CG_) + (oc * 16 + lm) * CG_
                                + kc2 * 32 + lg * 8;
                const float4 w0 = *reinterpret_cast<const float4*>(wr);
                const float4 w1 = *reinterpret_cast<const float4*>(wr + 4);
                union { unsigned int u[4]; short8 v; } aw;
                aw.u[0] = pk2(w0.x, w0.y); aw.u[1] = pk2(w0.z, w0.w);
                aw.u[2] = pk2(w1.x, w1.y); aw.u[3] = pk2(w1.z, w1.w);
                ca = MFMA16(aw.v, bf[g4 * 2 + kc2], ca);
            }
#pragma unroll
            for (int r = 0; r < 4; r++) {
                const int c = g4 * 64 + oc * 16 + lg * 4 + r;
                vout[(size_t)c * N_ + n] = f2bf(ca[r] + bv[c]);
            }
        }
    }
}

// ---------------------------------------------------------------------------
// Kernel 2: l2z[d][b][n] = -log2( sum_m exp2(s'[n][m]) ), rank-8 padded MFMA.
// grid(N/64, B, 2), block 256 (wave w owns n-rows w*16..w*16+15).
// ---------------------------------------------------------------------------
__global__ __launch_bounds__(256) void zcalc(unsigned short* __restrict__ wsu,
                                             float* __restrict__ wsf)
{
    const int d = blockIdx.z;
    const int b = blockIdx.y;
    const int t = threadIdx.x;
    const int w = t >> 6;
    const int l = t & 63;
    const int n0 = blockIdx.x * 64;

    const unsigned short* qT = wsu + QT_OFF + (size_t)(d * B_ + b) * N_ * 8;
    const unsigned short* kT = wsu + KT_OFF + (size_t)(d * B_ + b) * N_ * 8;

    // A-frag: q rows (lanes>=16 garbage, annihilated by B=0 padding)
    const short8 afrag = *reinterpret_cast<const short8*>(
        qT + (size_t)(n0 + w * 16 + (l & 15)) * 8);

    float zacc[4] = {0.f, 0.f, 0.f, 0.f};
    const f32x4 zero = {0.f, 0.f, 0.f, 0.f};

    for (int mt = 0; mt < 64; mt++) {
        short8 bk[4];
#pragma unroll
        for (int kb = 0; kb < 4; kb++) {
            if (l < 16)
                bk[kb] = *reinterpret_cast<const short8*>(
                    kT + (size_t)(mt * 64 + kb * 16 + l) * 8);
            else
                bk[kb] = short8{0, 0, 0, 0, 0, 0, 0, 0};
        }
#pragma unroll
        for (int kb = 0; kb < 4; kb++) {
            f32x4 sv = MFMA16(afrag, bk[kb], zero);
#pragma unroll
            for (int r = 0; r < 4; r++) zacc[r] += EXP2F(sv[r]);
        }
    }

#pragma unroll
    for (int r = 0; r < 4; r++) {
        float v = zacc[r];
        v += __shfl_xor(v, 1);
        v += __shfl_xor(v, 2);
        v += __shfl_xor(v, 4);
        v += __shfl_xor(v, 8);
        if ((l & 15) == 0) {
            const int n = n0 + w * 16 + (l >> 4) * 4 + r;
            wsf[L2Z_OFFF + (size_t)(d * B_ + b) * N_ + n] = -__log2f(v);
        }
    }
}

// ---------------------------------------------------------------------------
// Kernel 3: out[c][m] = f[c][m] + beta * sum_n v[c][n] * exp2(s'[n][m]+l2z[n])
// Tile 128c x 64m x BK=64. grid(64 m, 2 c, 4 db) = 512 blocks, 256 thr.
// A (v) frags direct from global (register double-buffered, preloaded one
// k-step ahead). Only the 9KB E-tile round-trips LDS. l2z folded into the
// E-MFMA C-operand (free normalization).
// ---------------------------------------------------------------------------
#define ES_STRIDE 72

__global__ __launch_bounds__(256, 2) void attn_gemm(
    const float* __restrict__ fL, const float* __restrict__ fU,
    const float* __restrict__ betap,
    const unsigned short* __restrict__ wsu,
    const float* __restrict__ wsf,
    float* __restrict__ out)
{
    const int d  = blockIdx.z >> 1;
    const int b  = blockIdx.z & 1;
    const int m0 = blockIdx.x * 64;
    const int c0 = blockIdx.y * 128;
    const int t  = threadIdx.x;
    const int w  = t >> 6;
    const int l  = t & 63;
    const int lm = l & 15;
    const int lg = l >> 4;
    const int wc = w & 1;        // c-half (64)
    const int wm = w >> 1;       // m-half (32)

    const unsigned short* qT = wsu + QT_OFF + (size_t)(d * B_ + b) * N_ * 8;
    const unsigned short* kT = wsu + KT_OFF + (size_t)(d * B_ + b) * N_ * 8;
    const unsigned short* V  = wsu + VZ_OFF + (size_t)(d * B_ + b) * C_ * N_;
    const float* l2z = wsf + L2Z_OFFF + (size_t)(d * B_ + b) * N_;
    const float* f = ((d == 0) ? fL : fU) + (size_t)b * C_ * N_;
    float*       o = out + (size_t)(d * B_ + b) * C_ * N_;

    __shared__ unsigned short Es[64 * ES_STRIDE];

    // persistent k-fragments (rank-8 real in lanes 0..15, zero elsewhere)
    short8 kf[4];
#pragma unroll
    for (int kb = 0; kb < 4; kb++) {
        if (l < 16)
            kf[kb] = *reinterpret_cast<const short8*>(
                kT + (size_t)(m0 + kb * 16 + l) * 8);
        else
            kf[kb] = short8{0, 0, 0, 0, 0, 0, 0, 0};
    }

    // hoisted row pointers
    const unsigned short* qp = qT + (size_t)(w * 16 + lm) * 8;
    const float*          zp = l2z + w * 16 + lg * 4;
    const unsigned short* Arow[4];
#pragma unroll
    for (int cb = 0; cb < 4; cb++)
        Arow[cb] = V + (size_t)(c0 + wc * 64 + cb * 16 + lm) * N_ + lg * 8;

    // preload k-step 0
    short8 qf = *reinterpret_cast<const short8*>(qp);
    float4 zf = *reinterpret_cast<const float4*>(zp);
    short8 Ac[8];
#pragma unroll
    for (int cb = 0; cb < 4; cb++)
#pragma unroll
        for (int kc = 0; kc < 2; kc++)
            Ac[cb * 2 + kc] = *reinterpret_cast<const short8*>(Arow[cb] + kc * 32);

    f32x4 acc[4][2];
#pragma unroll
    for (int cb = 0; cb < 4; cb++)
#pragma unroll
        for (int mb = 0; mb < 2; mb++) acc[cb][mb] = f32x4{0.f, 0.f, 0.f, 0.f};

    for (int i = 0; i < 64; i++) {
        const int n1 = (i == 63) ? 0 : (i + 1) * 64;   // clamped overread guard

        __syncthreads();
        // ---- phase 1: E-gen (normalization folded into C-operand) ----
        {
            const f32x4 cz = {zf.x, zf.y, zf.z, zf.w};
#pragma unroll
            for (int kb = 0; kb < 4; kb++) {
                f32x4 sv = MFMA16(qf, kf[kb], cz);
                uint2 p;
                p.x = pk2(EXP2F(sv[0]), EXP2F(sv[1]));
                p.y = pk2(EXP2F(sv[2]), EXP2F(sv[3]));
                *reinterpret_cast<uint2*>(
                    Es + (kb * 16 + lm) * ES_STRIDE + w * 16 + lg * 4) = p;
            }
        }
        __syncthreads();

        // ---- phase 2: preload next k-step, then main MFMAs ----
        short8 qn = *reinterpret_cast<const short8*>(qp + (size_t)n1 * 8);
        float4 zn = *reinterpret_cast<const float4*>(zp + n1);
        short8 An[8];
#pragma unroll
        for (int cb = 0; cb < 4; cb++)
#pragma unroll
            for (int kc = 0; kc < 2; kc++)
                An[cb * 2 + kc] = *reinterpret_cast<const short8*>(
                    Arow[cb] + n1 + kc * 32);

#pragma unroll
        for (int mb = 0; mb < 2; mb++) {
#pragma unroll
            for (int kc = 0; kc < 2; kc++) {
                const short8 Bf = *reinterpret_cast<const short8*>(
                    Es + (wm * 32 + mb * 16 + lm) * ES_STRIDE + kc * 32 + lg * 8);
#pragma unroll
                for (int cb = 0; cb < 4; cb++)
                    acc[cb][mb] = MFMA16(Ac[cb * 2 + kc], Bf, acc[cb][mb]);
            }
        }

        qf = qn; zf = zn;
#pragma unroll
        for (int j = 0; j < 8; j++) Ac[j] = An[j];
    }

    // ---- epilogue: out = f + beta * acc ----
    const float beta = *betap;
#pragma unroll
    for (int cb = 0; cb < 4; cb++) {
#pragma unroll
        for (int mb = 0; mb < 2; mb++) {
            const int c = c0 + wc * 64 + cb * 16 + lg * 4;
            const int m = m0 + wm * 32 + mb * 16 + lm;
#pragma unroll
            for (int r = 0; r < 4; r++) {
                const size_t off = (size_t)(c + r) * N_ + m;
                o[off] = f[off] + beta * acc[cb][mb][r];
            }
        }
    }
}

// ---------------------------------------------------------------------------
extern "C" void kernel_launch(void* const* d_in, const int* in_sizes, int n_in,
                              void* d_out, int out_size, void* d_ws, size_t ws_size,
                              hipStream_t stream)
{
    const float* fL   = (const float*)d_in[0];
    const float* fU   = (const float*)d_in[1];
    const float* qL_w = (const float*)d_in[2];
    const float* qL_b = (const float*)d_in[3];
    const float* kU_w = (const float*)d_in[4];
    const float* kU_b = (const float*)d_in[5];
    const float* vU_w = (const float*)d_in[6];
    const float* vU_b = (const float*)d_in[7];
    const float* qU_w = (const float*)d_in[8];
    const float* qU_b = (const float*)d_in[9];
    const float* kL_w = (const float*)d_in[10];
    const float* kL_b = (const float*)d_in[11];
    const float* vL_w = (const float*)d_in[12];
    const float* vL_b = (const float*)d_in[13];
    const float* beta = (const float*)d_in[14];

    unsigned short* wsu = (unsigned short*)d_ws;
    float*          wsf = (float*)d_ws;
    float*          outf = (float*)d_out;

    fused_pre<<<dim3(64, 1, 4), 256, 0, stream>>>(
        fL, fU, qL_w, qL_b, kU_w, kU_b, vU_w, vU_b,
        qU_w, qU_b, kL_w, kL_b, vL_w, vL_b, wsu);

    zcalc<<<dim3(64, B_, 2), 256, 0, stream>>>(wsu, wsf);

    attn_gemm<<<dim3(64, 2, 4), 256, 0, stream>>>(
        fL, fU, beta, wsu, wsf, outf);
}